// Round 1
// baseline (168.432 us; speedup 1.0000x reference)
//
#include <hip/hip_runtime.h>
#include <cstdint>

#define NROWS 2000   // pred boxes per image
#define MCOLS 200    // gt boxes per image
#define BIMG  128    // images
#define NTHR  5      // thresholds 0.5..0.7 step 0.05

// --- IoU helpers: bit-exact vs numpy reference (no fma contraction, IEEE div) ---

__device__ __forceinline__ float box_area(const float4 b) {
#pragma clang fp contract(off)
    return (b.z - b.x) * (b.w - b.y);
}

__device__ __forceinline__ float iou_pair(const float4 p, const float4 g,
                                          const float area1, const float area2) {
#pragma clang fp contract(off)
    float ltx = fmaxf(p.x, g.x);
    float lty = fmaxf(p.y, g.y);
    float rbx = fminf(p.z, g.z);
    float rby = fminf(p.w, g.w);
    float wx = fmaxf(rbx - ltx, 0.0f);
    float wy = fmaxf(rby - lty, 0.0f);
    float inter = wx * wy;
    float uni = (area1 + area2) - inter;   // reference order: (a1 + a2) - inter
    return inter / uni;
}

// --- Phase 1: full-row max IoU per (image, pred row). One thread per row. ---
__global__ void __launch_bounds__(256) rowmax_kernel(
        const float4* __restrict__ pred, const float4* __restrict__ gt,
        float* __restrict__ rowmax) {
    const int b = blockIdx.y;
    const int i = blockIdx.x * 256 + threadIdx.x;
    if (i >= NROWS) return;
    const float4 p = pred[b * NROWS + i];
    const float area1 = box_area(p);
    const float4* g = gt + b * MCOLS;   // uniform across wave -> scalar loads
    float best = -1.0f;
    for (int j = 0; j < MCOLS; ++j) {
        const float4 gb = g[j];
        best = fmaxf(best, iou_pair(p, gb, area1, box_area(gb)));
    }
    rowmax[b * NROWS + i] = best;
}

// --- Phase 2: one wave per (image, threshold). Exact sequential greedy over
//     only the rows whose full-row max >= threshold (others can't hit). ---
__global__ void __launch_bounds__(64) greedy_kernel(
        const float4* __restrict__ pred, const float4* __restrict__ gt,
        const float* __restrict__ rowmax, float* __restrict__ prec) {
    const int t = blockIdx.x;      // threshold index
    const int b = blockIdx.y;      // image index
    const int lane = threadIdx.x;  // 0..63
    // match np.arange(0.5, 0.75, 0.05): start + i*step in double, cast f32
    const float thr = (float)(0.5 + 0.05 * (double)t);

    // lane owns columns lane, lane+64, lane+128, lane+192(lanes 0..7 only)
    float4 g0, g1, g2, g3;
    float a20, a21, a22, a23;
    bool mt0 = false, mt1 = false, mt2 = false, mt3 = false;
    g0 = gt[b * MCOLS + lane];          a20 = box_area(g0);
    g1 = gt[b * MCOLS + lane + 64];     a21 = box_area(g1);
    g2 = gt[b * MCOLS + lane + 128];    a22 = box_area(g2);
    if (lane < MCOLS - 192) { g3 = gt[b * MCOLS + lane + 192]; a23 = box_area(g3); }
    else { g3 = make_float4(0.f, 0.f, 0.f, 0.f); a23 = 0.0f; }  // dummy -> iou 0, never >= thr

    int tp = 0;
    const int nchunk = (NROWS + 63) >> 6;
    for (int c = 0; c < nchunk; ++c) {
        const int row = (c << 6) + lane;
        const float mv = (row < NROWS) ? rowmax[b * NROWS + row] : -1.0f;
        unsigned long long act = __ballot(mv >= thr);
        while (act) {
            const int s = __ffsll(act) - 1;   // ascending row order (greedy order!)
            act &= act - 1;
            const int r = (c << 6) + s;
            const float4 p = pred[b * NROWS + r];   // uniform -> broadcast
            const float area1 = box_area(p);
            const float io0 = mt0 ? -1.0f : iou_pair(p, g0, area1, a20);
            const float io1 = mt1 ? -1.0f : iou_pair(p, g1, area1, a21);
            const float io2 = mt2 ? -1.0f : iou_pair(p, g2, area1, a22);
            const float io3 = mt3 ? -1.0f : iou_pair(p, g3, area1, a23);
            float wmax = fmaxf(fmaxf(io0, io1), fmaxf(io2, io3));
#pragma unroll
            for (int off = 32; off; off >>= 1)
                wmax = fmaxf(wmax, __shfl_xor(wmax, off));
            if (wmax >= thr) {               // uniform branch
                // find the (first) column achieving the max; matched cols are -1,
                // dummy cols are 0 < thr, so equality only fires on real candidates
                int lc = 1 << 30;
                if (io3 == wmax) lc = lane + 192;
                if (io2 == wmax) lc = lane + 128;
                if (io1 == wmax) lc = lane + 64;
                if (io0 == wmax) lc = lane;
                const unsigned long long cm = __ballot(lc < (1 << 30));
                const int src = __ffsll(cm) - 1;
                const int col = __builtin_amdgcn_readlane(lc, src);
                const bool own = (lane == (col & 63));
                const int kk = col >> 6;
                mt0 = mt0 || (own && kk == 0);
                mt1 = mt1 || (own && kk == 1);
                mt2 = mt2 || (own && kk == 2);
                mt3 = mt3 || (own && kk == 3);
                ++tp;
            }
        }
    }
    if (lane == 0) {
        // fp = NROWS - tp, fn = MCOLS - tp  =>  prec = tp / (NROWS + MCOLS - tp)
        prec[b * NTHR + t] = (float)tp / (float)(NROWS + MCOLS - tp);
    }
}

// --- Phase 3: mean over thresholds per image, then mean over images. ---
__global__ void __launch_bounds__(64) finalize_kernel(
        const float* __restrict__ prec, float* __restrict__ out) {
    const int lane = threadIdx.x;
    float s = 0.0f;
    for (int b = lane; b < BIMG; b += 64) {
        float pi = 0.0f;
#pragma unroll
        for (int t = 0; t < NTHR; ++t) pi += prec[b * NTHR + t];
        s += pi / (float)NTHR;
    }
#pragma unroll
    for (int off = 32; off; off >>= 1) s += __shfl_xor(s, off);
    if (lane == 0) out[0] = s / (float)BIMG;
}

extern "C" void kernel_launch(void* const* d_in, const int* in_sizes, int n_in,
                              void* d_out, int out_size, void* d_ws, size_t ws_size,
                              hipStream_t stream) {
    const float4* pred = (const float4*)d_in[0];
    const float4* gt   = (const float4*)d_in[1];
    float* out = (float*)d_out;

    float* ws_m = (float*)d_ws;                 // BIMG*NROWS floats (row maxima)
    float* ws_p = ws_m + BIMG * NROWS;          // BIMG*NTHR floats (per-task precision)

    dim3 g1((NROWS + 255) / 256, BIMG);
    rowmax_kernel<<<g1, dim3(256), 0, stream>>>(pred, gt, ws_m);

    dim3 g2(NTHR, BIMG);
    greedy_kernel<<<g2, dim3(64), 0, stream>>>(pred, gt, ws_m, ws_p);

    finalize_kernel<<<dim3(1), dim3(64), 0, stream>>>(ws_p, out);
}

// Round 2
// 125.866 us; speedup vs baseline: 1.3382x; 1.3382x over previous
//
#include <hip/hip_runtime.h>
#include <cstdint>

#define NROWS 2000   // pred boxes per image
#define MCOLS 200    // gt boxes per image
#define BIMG  128    // images
#define NTHR  5      // thresholds 0.5..0.7 step 0.05
#define NWORDS 32    // ceil(NROWS/64)
#define CAP   1024   // LDS-staged candidate cap (fallback path beyond)

typedef unsigned long long ull;

// --- exact IoU: bit-identical to numpy reference (contract off, IEEE div) ---
__device__ __forceinline__ float box_area(const float4 b) {
#pragma clang fp contract(off)
    return (b.z - b.x) * (b.w - b.y);
}

__device__ __forceinline__ float iou_exact(const float4 p, const float4 g,
                                           const float area1, const float area2) {
#pragma clang fp contract(off)
    float ltx = fmaxf(p.x, g.x), lty = fmaxf(p.y, g.y);
    float rbx = fminf(p.z, g.z), rby = fminf(p.w, g.w);
    float wx = fmaxf(rbx - ltx, 0.0f), wy = fmaxf(rby - lty, 0.0f);
    float inter = wx * wy;
    float uni = (area1 + area2) - inter;   // reference order
    return inter / uni;
}

// --- fast approx IoU (v_rcp), used ONLY for screening with >=1e-3 margin ---
__device__ __forceinline__ float iou_approx(const float4 p, const float4 g,
                                            const float area1, const float area2) {
    float ltx = fmaxf(p.x, g.x), lty = fmaxf(p.y, g.y);
    float rbx = fminf(p.z, g.z), rby = fminf(p.w, g.w);
    float wx = fmaxf(rbx - ltx, 0.0f), wy = fmaxf(rby - lty, 0.0f);
    float inter = wx * wy;
    float uni = (area1 + area2) - inter;
    return inter * __builtin_amdgcn_rcpf(uni);   // rel err ~1e-7 << 1e-3 margin
}

// --- Phase 1: approx full-row max IoU per (image,row). VALU-bound, full occ. ---
__global__ void __launch_bounds__(256) rowmax_kernel(
        const float4* __restrict__ pred, const float4* __restrict__ gt,
        float* __restrict__ rowmax) {
    __shared__ float4 gsh[MCOLS];
    __shared__ float  gar[MCOLS];
    const int b = blockIdx.y;
    if (threadIdx.x < MCOLS) {
        float4 gb = gt[b * MCOLS + threadIdx.x];
        gsh[threadIdx.x] = gb;
        gar[threadIdx.x] = box_area(gb);
    }
    __syncthreads();
    const int r = blockIdx.x * 256 + threadIdx.x;
    if (r >= NROWS) return;
    const float4 p = pred[b * NROWS + r];
    const float a1 = box_area(p);
    float best = 0.0f;
#pragma unroll 8
    for (int j = 0; j < MCOLS; ++j)
        best = fmaxf(best, iou_approx(p, gsh[j], a1, gar[j]));
    rowmax[b * NROWS + r] = best;
}

// one exact greedy step over a candidate row (p, a1); mask state in regs
__device__ __forceinline__ void greedy_step(
        const float4 p, const float a1, const float thr, const int lane,
        const float4 g0, const float4 g1, const float4 g2, const float4 g3,
        const float a20, const float a21, const float a22, const float a23,
        bool& mt0, bool& mt1, bool& mt2, bool& mt3, int& tp) {
    // raw IoUs are mask-independent -> pipelineable across iterations
    float io0 = iou_exact(p, g0, a1, a20);
    float io1 = iou_exact(p, g1, a1, a21);
    float io2 = iou_exact(p, g2, a1, a22);
    float io3 = iou_exact(p, g3, a1, a23);  // dummy cols (zero box) give 0
    float m0 = mt0 ? 0.0f : io0;            // masked cols -> 0 (< thr, can't win)
    float m1 = mt1 ? 0.0f : io1;
    float m2 = mt2 ? 0.0f : io2;
    float m3 = mt3 ? 0.0f : io3;
    float wmax = fmaxf(fmaxf(m0, m1), fmaxf(m2, m3));
#pragma unroll
    for (int off = 32; off; off >>= 1)
        wmax = fmaxf(wmax, __shfl_xor(wmax, off));
    if (wmax >= thr) {                       // uniform branch
        // first (lowest) column achieving the max == reference argmax
        ull b0 = __ballot(m0 == wmax);
        ull b1 = __ballot(m1 == wmax);
        ull b2 = __ballot(m2 == wmax);
        ull b3 = __ballot(m3 == wmax);
        int col;
        if (b0)      col =       __ffsll(b0) - 1;
        else if (b1) col =  64 + __ffsll(b1) - 1;
        else if (b2) col = 128 + __ffsll(b2) - 1;
        else         col = 192 + __ffsll(b3) - 1;
        const bool own = (lane == (col & 63));
        const int kk = col >> 6;
        mt0 = mt0 || (own && kk == 0);
        mt1 = mt1 || (own && kk == 1);
        mt2 = mt2 || (own && kk == 2);
        mt3 = mt3 || (own && kk == 3);
        ++tp;
    }
}

// --- Phase 2: one block per image, 5 waves = 5 thresholds.
//     Build candidate list once, stage boxes in LDS, greedy in-register. ---
__global__ void __launch_bounds__(320) greedy_kernel(
        const float4* __restrict__ pred, const float4* __restrict__ gt,
        const float* __restrict__ rowmax, float* __restrict__ perimg) {
    __shared__ float4 gsh[MCOLS];
    __shared__ float  gar[MCOLS];
    __shared__ float  rm_full[NROWS];
    __shared__ ull    words[NWORDS];
    __shared__ int    rows_l[NROWS];
    __shared__ float4 cb[CAP];
    __shared__ float  ca[CAP];
    __shared__ float  crm[CAP];
    __shared__ int    ncand_sh;
    __shared__ float  precs[NTHR];

    const int b    = blockIdx.x;
    const int tid  = threadIdx.x;
    const int wave = tid >> 6;    // 0..4
    const int lane = tid & 63;

    // 1) parallel screen: each wave ballots its rowmax words (candidates for
    //    ANY threshold: approx >= 0.4995 covers exact >= 0.5 with margin)
    for (int c = wave; c < NWORDS; c += NTHR) {
        const int row = c * 64 + lane;
        const float mv = (row < NROWS) ? rowmax[b * NROWS + row] : 0.0f;
        const ull w = __ballot(mv >= 0.4995f);
        if (row < NROWS) rm_full[row] = mv;
        if (lane == 0) words[c] = w;
    }
    __syncthreads();

    // 2) wave 0 compacts (ascending row order); waves 1-4 stage gt boxes
    if (wave == 0) {
        int n = 0;
        for (int c = 0; c < NWORDS; ++c) {
            const ull w = words[c];
            if ((w >> lane) & 1ull) {
                const int rank = n + __popcll(w & ((1ull << lane) - 1ull));
                rows_l[rank] = c * 64 + lane;
            }
            n += __popcll(w);
        }
        if (lane == 0) ncand_sh = n;
    } else {
        const int gi = tid - 64;   // 0..255
        if (gi < MCOLS) {
            const float4 gb = gt[b * MCOLS + gi];
            gsh[gi] = gb;
            gar[gi] = box_area(gb);
        }
    }
    __syncthreads();

    // 3) stage candidate pred boxes into LDS (shared by all 5 waves)
    const int ncand  = ncand_sh;
    const int nstage = min(ncand, CAP);
    for (int k = tid; k < nstage; k += 320) {
        const int row = rows_l[k];
        const float4 pb = pred[b * NROWS + row];
        cb[k] = pb;
        ca[k] = box_area(pb);
        crm[k] = rm_full[row];
    }
    __syncthreads();

    // 4) each wave runs exact greedy for its threshold
    const float thr = (float)(0.5 + 0.05 * (double)wave);  // == np.arange
    const float skipthr = thr - 1e-3f;                     // approx-safe skip
    const float4 g0 = gsh[lane];
    const float4 g1 = gsh[lane + 64];
    const float4 g2 = gsh[lane + 128];
    float4 g3; float a23;
    if (lane < MCOLS - 192) { g3 = gsh[lane + 192]; a23 = gar[lane + 192]; }
    else { g3 = make_float4(0.f, 0.f, 0.f, 0.f); a23 = 0.0f; }  // iou -> 0
    const float a20 = gar[lane], a21 = gar[lane + 64], a22 = gar[lane + 128];

    bool mt0 = false, mt1 = false, mt2 = false, mt3 = false;
    int tp = 0;
    for (int k = 0; k < nstage; ++k) {
        if (crm[k] < skipthr) continue;      // provably no hit (pure fp)
        greedy_step(cb[k], ca[k], thr, lane, g0, g1, g2, g3,
                    a20, a21, a22, a23, mt0, mt1, mt2, mt3, tp);
    }
    for (int k = CAP; k < ncand; ++k) {      // adversarial overflow fallback
        const int row = rows_l[k];
        if (rm_full[row] < skipthr) continue;
        const float4 p = pred[b * NROWS + row];
        greedy_step(p, box_area(p), thr, lane, g0, g1, g2, g3,
                    a20, a21, a22, a23, mt0, mt1, mt2, mt3, tp);
    }
    // fp = NROWS - tp, fn = MCOLS - tp  =>  prec = tp / (NROWS + MCOLS - tp)
    if (lane == 0) precs[wave] = (float)tp / (float)(NROWS + MCOLS - tp);
    __syncthreads();
    if (tid == 0) {
        float s = 0.0f;
#pragma unroll
        for (int t = 0; t < NTHR; ++t) s += precs[t];
        perimg[b] = s / (float)NTHR;
    }
}

// --- Phase 3: mean over images ---
__global__ void __launch_bounds__(64) finalize_kernel(
        const float* __restrict__ perimg, float* __restrict__ out) {
    const int lane = threadIdx.x;
    float s = perimg[lane] + perimg[lane + 64];
#pragma unroll
    for (int off = 32; off; off >>= 1) s += __shfl_xor(s, off);
    if (lane == 0) out[0] = s / (float)BIMG;
}

extern "C" void kernel_launch(void* const* d_in, const int* in_sizes, int n_in,
                              void* d_out, int out_size, void* d_ws, size_t ws_size,
                              hipStream_t stream) {
    const float4* pred = (const float4*)d_in[0];
    const float4* gt   = (const float4*)d_in[1];
    float* out = (float*)d_out;

    float* ws_m  = (float*)d_ws;            // BIMG*NROWS approx row maxima
    float* ws_pi = ws_m + BIMG * NROWS;     // BIMG per-image precision means

    dim3 g1((NROWS + 255) / 256, BIMG);
    rowmax_kernel<<<g1, dim3(256), 0, stream>>>(pred, gt, ws_m);

    greedy_kernel<<<dim3(BIMG), dim3(320), 0, stream>>>(pred, gt, ws_m, ws_pi);

    finalize_kernel<<<dim3(1), dim3(64), 0, stream>>>(ws_pi, out);
}

// Round 3
// 124.757 us; speedup vs baseline: 1.3501x; 1.0089x over previous
//
#include <hip/hip_runtime.h>
#include <cstdint>

#define NROWS 2000   // pred boxes per image
#define MCOLS 200    // gt boxes per image
#define BIMG  128    // images
#define NTHR  5      // thresholds 0.5..0.7 step 0.05
#define NWORDS 32    // ceil(NROWS/64)
#define CAP   1024   // LDS-staged candidate cap (fallback path beyond)

typedef unsigned long long ull;

// --- exact IoU: bit-identical to numpy reference (contract off, IEEE div) ---
__device__ __forceinline__ float box_area(const float4 b) {
#pragma clang fp contract(off)
    return (b.z - b.x) * (b.w - b.y);
}

__device__ __forceinline__ float iou_exact(const float4 p, const float4 g,
                                           const float area1, const float area2) {
#pragma clang fp contract(off)
    float ltx = fmaxf(p.x, g.x), lty = fmaxf(p.y, g.y);
    float rbx = fminf(p.z, g.z), rby = fminf(p.w, g.w);
    float wx = fmaxf(rbx - ltx, 0.0f), wy = fmaxf(rby - lty, 0.0f);
    float inter = wx * wy;
    float uni = (area1 + area2) - inter;   // reference order
    return inter / uni;
}

// --- fast approx IoU (v_rcp), used ONLY for screening with >=1e-3 margin ---
__device__ __forceinline__ float iou_approx(const float4 p, const float4 g,
                                            const float area1, const float area2) {
    float ltx = fmaxf(p.x, g.x), lty = fmaxf(p.y, g.y);
    float rbx = fminf(p.z, g.z), rby = fminf(p.w, g.w);
    float wx = fmaxf(rbx - ltx, 0.0f), wy = fmaxf(rby - lty, 0.0f);
    float inter = wx * wy;
    float uni = (area1 + area2) - inter;
    return inter * __builtin_amdgcn_rcpf(uni);   // rel err ~1e-7 << 1e-3 margin
}

// --- Phase 1: approx full-row max IoU per (image,row). VALU-bound, full occ. ---
__global__ void __launch_bounds__(256) rowmax_kernel(
        const float4* __restrict__ pred, const float4* __restrict__ gt,
        float* __restrict__ rowmax) {
    __shared__ float4 gsh[MCOLS];
    __shared__ float  gar[MCOLS];
    const int b = blockIdx.y;
    if (threadIdx.x < MCOLS) {
        float4 gb = gt[b * MCOLS + threadIdx.x];
        gsh[threadIdx.x] = gb;
        gar[threadIdx.x] = box_area(gb);
    }
    __syncthreads();
    const int r = blockIdx.x * 256 + threadIdx.x;
    if (r >= NROWS) return;
    const float4 p = pred[b * NROWS + r];
    const float a1 = box_area(p);
    float best = 0.0f;
#pragma unroll 8
    for (int j = 0; j < MCOLS; ++j)
        best = fmaxf(best, iou_approx(p, gsh[j], a1, gar[j]));
    rowmax[b * NROWS + r] = best;
}

// one exact greedy step over a candidate row (p, a1); mask state in regs
__device__ __forceinline__ void greedy_step(
        const float4 p, const float a1, const float thr, const int lane,
        const float4 g0, const float4 g1, const float4 g2, const float4 g3,
        const float a20, const float a21, const float a22, const float a23,
        bool& mt0, bool& mt1, bool& mt2, bool& mt3, int& tp) {
    // raw IoUs are mask-independent -> pipelineable across iterations
    float io0 = iou_exact(p, g0, a1, a20);
    float io1 = iou_exact(p, g1, a1, a21);
    float io2 = iou_exact(p, g2, a1, a22);
    float io3 = iou_exact(p, g3, a1, a23);  // dummy cols (zero box) give 0
    float m0 = mt0 ? 0.0f : io0;            // masked cols -> 0 (< thr, can't win)
    float m1 = mt1 ? 0.0f : io1;
    float m2 = mt2 ? 0.0f : io2;
    float m3 = mt3 ? 0.0f : io3;
    float wmax = fmaxf(fmaxf(m0, m1), fmaxf(m2, m3));
#pragma unroll
    for (int off = 32; off; off >>= 1)
        wmax = fmaxf(wmax, __shfl_xor(wmax, off));
    if (wmax >= thr) {                       // uniform branch
        // first (lowest) column achieving the max == reference argmax
        ull b0 = __ballot(m0 == wmax);
        ull b1 = __ballot(m1 == wmax);
        ull b2 = __ballot(m2 == wmax);
        ull b3 = __ballot(m3 == wmax);
        int col;
        if (b0)      col =       __ffsll(b0) - 1;
        else if (b1) col =  64 + __ffsll(b1) - 1;
        else if (b2) col = 128 + __ffsll(b2) - 1;
        else         col = 192 + __ffsll(b3) - 1;
        const bool own = (lane == (col & 63));
        const int kk = col >> 6;
        mt0 = mt0 || (own && kk == 0);
        mt1 = mt1 || (own && kk == 1);
        mt2 = mt2 || (own && kk == 2);
        mt3 = mt3 || (own && kk == 3);
        ++tp;
    }
}

// --- Phase 2: one block per image, 5 waves = 5 thresholds.
//     Build candidate list once, stage boxes in LDS, greedy in-register. ---
__global__ void __launch_bounds__(320) greedy_kernel(
        const float4* __restrict__ pred, const float4* __restrict__ gt,
        const float* __restrict__ rowmax, float* __restrict__ perimg) {
    __shared__ float4 gsh[MCOLS];
    __shared__ float  gar[MCOLS];
    __shared__ float  rm_full[NROWS];
    __shared__ ull    words[NWORDS];
    __shared__ int    rows_l[NROWS];
    __shared__ float4 cb[CAP];
    __shared__ float  ca[CAP];
    __shared__ float  crm[CAP];
    __shared__ int    ncand_sh;
    __shared__ float  precs[NTHR];

    const int b    = blockIdx.x;
    const int tid  = threadIdx.x;
    const int wave = tid >> 6;    // 0..4
    const int lane = tid & 63;

    // 1) parallel screen: each wave ballots its rowmax words (candidates for
    //    ANY threshold: approx >= 0.4995 covers exact >= 0.5 with margin)
    for (int c = wave; c < NWORDS; c += NTHR) {
        const int row = c * 64 + lane;
        const float mv = (row < NROWS) ? rowmax[b * NROWS + row] : 0.0f;
        const ull w = __ballot(mv >= 0.4995f);
        if (row < NROWS) rm_full[row] = mv;
        if (lane == 0) words[c] = w;
    }
    __syncthreads();

    // 2) wave 0 compacts (ascending row order); waves 1-4 stage gt boxes
    if (wave == 0) {
        int n = 0;
        for (int c = 0; c < NWORDS; ++c) {
            const ull w = words[c];
            if ((w >> lane) & 1ull) {
                const int rank = n + __popcll(w & ((1ull << lane) - 1ull));
                rows_l[rank] = c * 64 + lane;
            }
            n += __popcll(w);
        }
        if (lane == 0) ncand_sh = n;
    } else {
        const int gi = tid - 64;   // 0..255
        if (gi < MCOLS) {
            const float4 gb = gt[b * MCOLS + gi];
            gsh[gi] = gb;
            gar[gi] = box_area(gb);
        }
    }
    __syncthreads();

    // 3) stage candidate pred boxes into LDS (shared by all 5 waves)
    const int ncand  = ncand_sh;
    const int nstage = min(ncand, CAP);
    for (int k = tid; k < nstage; k += 320) {
        const int row = rows_l[k];
        const float4 pb = pred[b * NROWS + row];
        cb[k] = pb;
        ca[k] = box_area(pb);
        crm[k] = rm_full[row];
    }
    __syncthreads();

    // 4) each wave runs exact greedy for its threshold
    const float thr = (float)(0.5 + 0.05 * (double)wave);  // == np.arange
    const float skipthr = thr - 1e-3f;                     // approx-safe skip
    const float4 g0 = gsh[lane];
    const float4 g1 = gsh[lane + 64];
    const float4 g2 = gsh[lane + 128];
    float4 g3; float a23;
    if (lane < MCOLS - 192) { g3 = gsh[lane + 192]; a23 = gar[lane + 192]; }
    else { g3 = make_float4(0.f, 0.f, 0.f, 0.f); a23 = 0.0f; }  // iou -> 0
    const float a20 = gar[lane], a21 = gar[lane + 64], a22 = gar[lane + 128];

    bool mt0 = false, mt1 = false, mt2 = false, mt3 = false;
    int tp = 0;
    for (int k = 0; k < nstage; ++k) {
        if (crm[k] < skipthr) continue;      // provably no hit (pure fp)
        greedy_step(cb[k], ca[k], thr, lane, g0, g1, g2, g3,
                    a20, a21, a22, a23, mt0, mt1, mt2, mt3, tp);
    }
    for (int k = CAP; k < ncand; ++k) {      // adversarial overflow fallback
        const int row = rows_l[k];
        if (rm_full[row] < skipthr) continue;
        const float4 p = pred[b * NROWS + row];
        greedy_step(p, box_area(p), thr, lane, g0, g1, g2, g3,
                    a20, a21, a22, a23, mt0, mt1, mt2, mt3, tp);
    }
    // fp = NROWS - tp, fn = MCOLS - tp  =>  prec = tp / (NROWS + MCOLS - tp)
    if (lane == 0) precs[wave] = (float)tp / (float)(NROWS + MCOLS - tp);
    __syncthreads();
    if (tid == 0) {
        float s = 0.0f;
#pragma unroll
        for (int t = 0; t < NTHR; ++t) s += precs[t];
        perimg[b] = s / (float)NTHR;
    }
}

// --- Phase 3: mean over images ---
__global__ void __launch_bounds__(64) finalize_kernel(
        const float* __restrict__ perimg, float* __restrict__ out) {
    const int lane = threadIdx.x;
    float s = perimg[lane] + perimg[lane + 64];
#pragma unroll
    for (int off = 32; off; off >>= 1) s += __shfl_xor(s, off);
    if (lane == 0) out[0] = s / (float)BIMG;
}

extern "C" void kernel_launch(void* const* d_in, const int* in_sizes, int n_in,
                              void* d_out, int out_size, void* d_ws, size_t ws_size,
                              hipStream_t stream) {
    const float4* pred = (const float4*)d_in[0];
    const float4* gt   = (const float4*)d_in[1];
    float* out = (float*)d_out;

    float* ws_m  = (float*)d_ws;            // BIMG*NROWS approx row maxima
    float* ws_pi = ws_m + BIMG * NROWS;     // BIMG per-image precision means

    dim3 g1((NROWS + 255) / 256, BIMG);
    rowmax_kernel<<<g1, dim3(256), 0, stream>>>(pred, gt, ws_m);

    greedy_kernel<<<dim3(BIMG), dim3(320), 0, stream>>>(pred, gt, ws_m, ws_pi);

    finalize_kernel<<<dim3(1), dim3(64), 0, stream>>>(ws_pi, out);
}

// Round 4
// 108.103 us; speedup vs baseline: 1.5581x; 1.1541x over previous
//
#include <hip/hip_runtime.h>
#include <cstdint>

#define NROWS 2000   // pred boxes per image
#define MCOLS 200    // gt boxes per image
#define BIMG  128    // images
#define NTHR  5      // thresholds 0.5..0.7 step 0.05
#define CAP   768    // per-image candidate entry capacity (expected ~76)
#define NPMAX 1024   // next pow2 >= CAP (LDS sort buffer)

typedef unsigned long long ull;

struct IouParts { float inter, uni; };

// --- exact sub-expressions: bit-identical to numpy reference (contract off) ---
__device__ __forceinline__ float box_area(const float4 b) {
#pragma clang fp contract(off)
    return (b.z - b.x) * (b.w - b.y);
}

__device__ __forceinline__ IouParts iou_parts(const float4 p, const float4 g,
                                              const float a1, const float a2) {
#pragma clang fp contract(off)
    float ltx = fmaxf(p.x, g.x), lty = fmaxf(p.y, g.y);
    float rbx = fminf(p.z, g.z), rby = fminf(p.w, g.w);
    float wx = fmaxf(rbx - ltx, 0.0f), wy = fmaxf(rby - lty, 0.0f);
    float inter = wx * wy;
    float uni = (a1 + a2) - inter;   // reference order
    return {inter, uni};
}

// --- Phase 1: all-pairs screen. Flag pairs with iou >= ~0.4993 (margin >>
//     rounding; any pair that can ever match at thr>=0.5 is caught), push
//     packed sort key (row asc | exact-iou desc | col asc) per image. ---
__global__ void __launch_bounds__(256) screen_kernel(
        const float4* __restrict__ pred, const float4* __restrict__ gt,
        int* __restrict__ counters, ull* __restrict__ entries) {
    __shared__ float4 gsh[MCOLS];
    __shared__ float  gar[MCOLS];
    const int b = blockIdx.y;
    if (threadIdx.x < MCOLS) {
        const float4 gb = gt[b * MCOLS + threadIdx.x];
        gsh[threadIdx.x] = gb;
        gar[threadIdx.x] = box_area(gb);
    }
    __syncthreads();
    const int r = blockIdx.x * 256 + threadIdx.x;
    if (r >= NROWS) return;
    const float4 p = pred[b * NROWS + r];
    const float a1 = box_area(p);
#pragma unroll 4
    for (int j = 0; j < MCOLS; ++j) {
        const IouParts ip = iou_parts(p, gsh[j], a1, gar[j]);
        if (ip.inter >= 0.4993f * ip.uni) {        // mul-compare, no div
            const float iou = ip.inter / ip.uni;   // exact IEEE == reference
            const int idx = atomicAdd(&counters[b], 1);
            if (idx < CAP)
                entries[b * CAP + idx] = ((ull)r << 40)
                    | ((ull)(__float_as_uint(iou) ^ 0xFFFFFFFFu) << 8)
                    | (ull)j;
        }
    }
}

// --- Phase 2: per image: bitonic-sort candidate keys (deterministic total
//     order erases atomic append order), then 5 lanes replay exact greedy
//     serially in registers (200-bit matched mask in 4 ulls). ---
__global__ void __launch_bounds__(64) match_kernel(
        const int* __restrict__ counters, const ull* __restrict__ entries,
        float* __restrict__ perimg) {
    __shared__ ull   keys[NPMAX];
    __shared__ float precs[NTHR];
    const int b = blockIdx.x;
    const int tid = threadIdx.x;
    const int n = min(counters[b], CAP);

    int np = 64;
    while (np < n) np <<= 1;                 // n<=768 -> np<=1024
    for (int i = tid; i < np; i += 64)
        keys[i] = (i < n) ? entries[b * CAP + i] : ~0ull;   // sentinels sort last
    __syncthreads();

    for (int k = 2; k <= np; k <<= 1) {
        for (int j = k >> 1; j > 0; j >>= 1) {
            for (int i = tid; i < np; i += 64) {
                const int ixj = i ^ j;
                if (ixj > i) {
                    const ull a = keys[i], c = keys[ixj];
                    const bool up = (i & k) == 0;
                    if ((a > c) == up) { keys[i] = c; keys[ixj] = a; }
                }
            }
            __syncthreads();
        }
    }

    if (tid < NTHR) {
        // match np.arange(0.5, 0.75, 0.05): start + i*step in double, cast f32
        const float thr = (float)(0.5 + 0.05 * (double)tid);
        ull m0 = 0, m1 = 0, m2 = 0, m3 = 0;
        int tp = 0, cur = -1;
        bool done = false;
        for (int e = 0; e < n; ++e) {
            const ull key = keys[e];         // uniform-ish LDS broadcast
            const int row = (int)(key >> 40);
            if (row != cur) { cur = row; done = false; }
            if (done) continue;              // row outcome already decided
            const int col = (int)(key & 0xFFull);
            const int w = col >> 6;
            const ull bit = 1ull << (col & 63);
            const ull mm = (w == 0) ? m0 : (w == 1) ? m1 : (w == 2) ? m2 : m3;
            if (mm & bit) continue;          // col matched -> next-best entry
            done = true;                     // best unmatched col found
            const uint ib = (uint)(key >> 8) ^ 0xFFFFFFFFu;
            if (__uint_as_float(ib) >= thr) {
                ++tp;
                if (w == 0) m0 |= bit; else if (w == 1) m1 |= bit;
                else if (w == 2) m2 |= bit; else m3 |= bit;
            }
        }
        // fp = NROWS - tp, fn = MCOLS - tp  =>  prec = tp / (N + M - tp)
        precs[tid] = (float)tp / (float)(NROWS + MCOLS - tp);
    }
    __syncthreads();
    if (tid == 0) {
        float s = 0.0f;
#pragma unroll
        for (int t = 0; t < NTHR; ++t) s += precs[t];
        perimg[b] = s / (float)NTHR;
    }
}

// --- Phase 3: mean over images ---
__global__ void __launch_bounds__(64) finalize_kernel(
        const float* __restrict__ perimg, float* __restrict__ out) {
    const int lane = threadIdx.x;
    float s = perimg[lane] + perimg[lane + 64];
#pragma unroll
    for (int off = 32; off; off >>= 1) s += __shfl_xor(s, off);
    if (lane == 0) out[0] = s / (float)BIMG;
}

extern "C" void kernel_launch(void* const* d_in, const int* in_sizes, int n_in,
                              void* d_out, int out_size, void* d_ws, size_t ws_size,
                              hipStream_t stream) {
    const float4* pred = (const float4*)d_in[0];
    const float4* gt   = (const float4*)d_in[1];
    float* out = (float*)d_out;

    int*   cnt     = (int*)d_ws;                                   // 128 ints
    ull*   entries = (ull*)((char*)d_ws + 512);                    // 128*CAP u64
    float* perimg  = (float*)((char*)d_ws + 512 + (size_t)BIMG * CAP * 8);

    hipMemsetAsync(cnt, 0, BIMG * sizeof(int), stream);            // capturable

    dim3 g1((NROWS + 255) / 256, BIMG);
    screen_kernel<<<g1, dim3(256), 0, stream>>>(pred, gt, cnt, entries);

    match_kernel<<<dim3(BIMG), dim3(64), 0, stream>>>(cnt, entries, perimg);

    finalize_kernel<<<dim3(1), dim3(64), 0, stream>>>(perimg, out);
}

// Round 5
// 95.588 us; speedup vs baseline: 1.7621x; 1.1309x over previous
//
#include <hip/hip_runtime.h>
#include <cstdint>

#define NROWS 2000   // pred boxes per image
#define MCOLS 200    // gt boxes per image
#define BIMG  128    // images
#define NTHR  5      // thresholds 0.5..0.7 step 0.05
#define CAP   768    // per-image candidate entry capacity (expected ~76)
#define NPMAX 1024   // next pow2 >= CAP (LDS sort buffer)

typedef unsigned long long ull;

// --- Phase 1: all-pairs screen. gt row is WAVE-UNIFORM -> scalar (s_load)
//     path, no LDS. Flag pairs with iou >= ~0.4993 via mul-compare (margin >>
//     rounding; any pair that can match at thr>=0.5 is caught). Push packed
//     sort key (row asc | exact-IEEE-iou desc | col asc) per image. ---
__global__ void __launch_bounds__(256) screen_kernel(
        const float4* __restrict__ pred, const float4* __restrict__ gt,
        int* __restrict__ counters, ull* __restrict__ entries) {
#pragma clang fp contract(off)
    const int b = blockIdx.y;
    const int r = blockIdx.x * 256 + threadIdx.x;
    const float4* __restrict__ g = gt + b * MCOLS;   // uniform across wave
    float4 p;
    if (r < NROWS) p = pred[b * NROWS + r];
    else p = make_float4(-1.f, -1.f, -1.f, -1.f);    // degenerate: inter=0, never flags
    const float a1 = (p.z - p.x) * (p.w - p.y);
#pragma unroll 2
    for (int j = 0; j < MCOLS; ++j) {
        const float4 gb = g[j];                       // uniform -> scalar load
        const float a2 = (gb.z - gb.x) * (gb.w - gb.y);
        const float ltx = fmaxf(p.x, gb.x), lty = fmaxf(p.y, gb.y);
        const float rbx = fminf(p.z, gb.z), rby = fminf(p.w, gb.w);
        const float wx = fmaxf(rbx - ltx, 0.0f), wy = fmaxf(rby - lty, 0.0f);
        const float inter = wx * wy;
        const float uni = (a1 + a2) - inter;          // reference order
        if (inter >= 0.4993f * uni) {                 // no division on hot path
            const float iou = inter / uni;            // exact IEEE == reference
            const int idx = atomicAdd(&counters[b], 1);
            if (idx < CAP)
                entries[(size_t)b * CAP + idx] = ((ull)r << 40)
                    | ((ull)(__float_as_uint(iou) ^ 0xFFFFFFFFu) << 8)
                    | (ull)j;
        }
    }
}

// --- Phase 2: per image: bitonic-sort candidate keys (deterministic total
//     order erases atomic append order), then 5 lanes replay exact greedy
//     BRANCHLESSLY in registers (200-bit matched mask in 4 ulls). ---
__global__ void __launch_bounds__(64) match_kernel(
        const int* __restrict__ counters, const ull* __restrict__ entries,
        float* __restrict__ perimg) {
    __shared__ ull   keys[NPMAX];
    __shared__ float precs[NTHR];
    const int b = blockIdx.x;
    const int tid = threadIdx.x;
    const int n = min(counters[b], CAP);

    int np = 64;
    while (np < n) np <<= 1;                 // n<=768 -> np<=1024
    for (int i = tid; i < np; i += 64)
        keys[i] = (i < n) ? entries[(size_t)b * CAP + i] : ~0ull;  // sentinels last
    __syncthreads();

    for (int k = 2; k <= np; k <<= 1) {
        for (int j = k >> 1; j > 0; j >>= 1) {
            for (int i = tid; i < np; i += 64) {
                const int ixj = i ^ j;
                if (ixj > i) {
                    const ull a = keys[i], c = keys[ixj];
                    if ((a > c) == ((i & k) == 0)) { keys[i] = c; keys[ixj] = a; }
                }
            }
            __syncthreads();
        }
    }

    if (tid < NTHR) {
        // match np.arange(0.5, 0.75, 0.05): start + i*step in double, cast f32
        const float thr = (float)(0.5 + 0.05 * (double)tid);
        const uint thr_inv = __float_as_uint(thr) ^ 0xFFFFFFFFu;
        ull m0 = 0, m1 = 0, m2 = 0, m3 = 0;
        int tp = 0, cur = -1;
        bool done = false;
#pragma unroll 4
        for (int e = 0; e < n; ++e) {
            const ull key = keys[e];              // induction addr -> prefetchable
            const int row = (int)(key >> 40);
            const int col = (int)(key & 0xFFull);
            const uint ib  = (uint)(key >> 8);    // inverted iou bits (low = high iou)
            const bool newrow = (row != cur);
            cur = row;
            const bool undecided = newrow || !done;
            const int w = col >> 6;
            const ull bit = 1ull << (col & 63);
            const ull mm = (w == 0) ? m0 : (w == 1) ? m1 : (w == 2) ? m2 : m3;
            const bool decide = undecided && ((mm & bit) == 0);  // best unmatched col
            const bool hit = decide && (ib <= thr_inv);          // iou >= thr
            tp += hit ? 1 : 0;
            const ull sb = hit ? bit : 0ull;
            m0 |= (w == 0) ? sb : 0ull;
            m1 |= (w == 1) ? sb : 0ull;
            m2 |= (w == 2) ? sb : 0ull;
            m3 |= (w == 3) ? sb : 0ull;
            done = decide || (done && !newrow);
        }
        // fp = NROWS - tp, fn = MCOLS - tp  =>  prec = tp / (N + M - tp)
        precs[tid] = (float)tp / (float)(NROWS + MCOLS - tp);
    }
    __syncthreads();
    if (tid == 0) {
        float s = 0.0f;
#pragma unroll
        for (int t = 0; t < NTHR; ++t) s += precs[t];
        perimg[b] = s / (float)NTHR;
    }
}

// --- Phase 3: mean over images ---
__global__ void __launch_bounds__(64) finalize_kernel(
        const float* __restrict__ perimg, float* __restrict__ out) {
    const int lane = threadIdx.x;
    float s = perimg[lane] + perimg[lane + 64];
#pragma unroll
    for (int off = 32; off; off >>= 1) s += __shfl_xor(s, off);
    if (lane == 0) out[0] = s / (float)BIMG;
}

extern "C" void kernel_launch(void* const* d_in, const int* in_sizes, int n_in,
                              void* d_out, int out_size, void* d_ws, size_t ws_size,
                              hipStream_t stream) {
    const float4* pred = (const float4*)d_in[0];
    const float4* gt   = (const float4*)d_in[1];
    float* out = (float*)d_out;

    int*   cnt     = (int*)d_ws;                                   // 128 ints
    ull*   entries = (ull*)((char*)d_ws + 512);                    // 128*CAP u64
    float* perimg  = (float*)((char*)d_ws + 512 + (size_t)BIMG * CAP * 8);

    hipMemsetAsync(cnt, 0, BIMG * sizeof(int), stream);            // capturable

    dim3 g1((NROWS + 255) / 256, BIMG);
    screen_kernel<<<g1, dim3(256), 0, stream>>>(pred, gt, cnt, entries);

    match_kernel<<<dim3(BIMG), dim3(64), 0, stream>>>(cnt, entries, perimg);

    finalize_kernel<<<dim3(1), dim3(64), 0, stream>>>(perimg, out);
}

// Round 7
// 89.770 us; speedup vs baseline: 1.8763x; 1.0648x over previous
//
#include <hip/hip_runtime.h>
#include <cstdint>

// Bit-exact vs numpy reference: no FMA contraction anywhere in this TU.
#pragma clang fp contract(off)

#define NROWS 2000   // pred boxes per image
#define MCOLS 200    // gt boxes per image
#define BIMG  128    // images
#define NTHR  5      // thresholds 0.5..0.7 step 0.05
#define CAP   768    // per-image candidate entry capacity (expected ~76)
#define NPMAX 1024   // next pow2 >= CAP (LDS sort buffer)
#define RPT   4      // rows per thread (ILP)
#define CSPLIT 8     // column chunks per image (TLP)
#define CPB   (MCOLS / CSPLIT)   // 25 gt cols per block

typedef unsigned long long ull;

// --- Phase 1: all-pairs screen, tiled for full occupancy + ILP.
//     Each block: 1024 rows x 25 cols of one image; gt tile in LDS.
//     Predicate inter >= 0.4993*uni (exact operands, margin >> ulp) catches
//     every pair that can match at thr >= 0.5. Hits push packed sort key
//     (row asc | exact-IEEE-iou desc | col asc). ---
__global__ void __launch_bounds__(256) screen_kernel(
        const float4* __restrict__ pred, const float4* __restrict__ gt,
        int* __restrict__ counters, ull* __restrict__ entries) {
    __shared__ float4 gsh[CPB];
    __shared__ float  gar[CPB];
    const int b    = blockIdx.z;
    const int cch  = blockIdx.y;           // column chunk
    const int tid  = threadIdx.x;
    if (tid < CPB) {
        const float4 gb = gt[b * MCOLS + cch * CPB + tid];
        gsh[tid] = gb;
        gar[tid] = (gb.z - gb.x) * (gb.w - gb.y);
    }
    __syncthreads();

    const int r0 = blockIdx.x * (256 * RPT) + tid;   // rows r0 + k*256
    float4 p[RPT];
    float  a1[RPT];
#pragma unroll
    for (int k = 0; k < RPT; ++k) {
        const int r = r0 + k * 256;
        p[k] = (r < NROWS) ? pred[b * NROWS + r]
                           : make_float4(-1.f, -1.f, -1.f, -1.f);  // never flags
        a1[k] = (p[k].z - p[k].x) * (p[k].w - p[k].y);
    }

#pragma unroll 5
    for (int j = 0; j < CPB; ++j) {
        const float4 gb = gsh[j];          // broadcast, conflict-free
        const float  a2 = gar[j];
#pragma unroll
        for (int k = 0; k < RPT; ++k) {
            const float ltx = fmaxf(p[k].x, gb.x), lty = fmaxf(p[k].y, gb.y);
            const float rbx = fminf(p[k].z, gb.z), rby = fminf(p[k].w, gb.w);
            const float wx = fmaxf(rbx - ltx, 0.0f), wy = fmaxf(rby - lty, 0.0f);
            const float inter = wx * wy;
            const float uni = (a1[k] + a2) - inter;   // reference order
            if (inter >= 0.4993f * uni) {             // no div on hot path
                const float iou = inter / uni;        // exact IEEE == reference
                const int idx = atomicAdd(&counters[b], 1);
                if (idx < CAP)
                    entries[(size_t)b * CAP + idx] =
                          ((ull)(r0 + k * 256) << 40)
                        | ((ull)(__float_as_uint(iou) ^ 0xFFFFFFFFu) << 8)
                        | (ull)(cch * CPB + j);
            }
        }
    }
}

// --- Phase 2: per image: bitonic-sort candidate keys (deterministic total
//     order erases atomic append order), then 5 lanes replay exact greedy
//     branchlessly in registers (200-bit matched mask in 4 ulls). ---
__global__ void __launch_bounds__(128) match_kernel(
        const int* __restrict__ counters, const ull* __restrict__ entries,
        float* __restrict__ perimg) {
    __shared__ ull   keys[NPMAX];
    __shared__ float precs[NTHR];
    const int b = blockIdx.x;
    const int tid = threadIdx.x;
    const int n = min(counters[b], CAP);

    int np = 128;
    while (np < n) np <<= 1;                 // n<=768 -> np<=1024
    for (int i = tid; i < np; i += 128)
        keys[i] = (i < n) ? entries[(size_t)b * CAP + i] : ~0ull;  // sentinels last
    __syncthreads();

    for (int k = 2; k <= np; k <<= 1) {
        for (int j = k >> 1; j > 0; j >>= 1) {
            for (int i = tid; i < np; i += 128) {
                const int ixj = i ^ j;
                if (ixj > i) {
                    const ull a = keys[i], c = keys[ixj];
                    if ((a > c) == ((i & k) == 0)) { keys[i] = c; keys[ixj] = a; }
                }
            }
            __syncthreads();
        }
    }

    if (tid < NTHR) {
        // match np.arange(0.5, 0.75, 0.05): start + i*step in double, cast f32
        const float thr = (float)(0.5 + 0.05 * (double)tid);
        const uint thr_inv = __float_as_uint(thr) ^ 0xFFFFFFFFu;
        ull m0 = 0, m1 = 0, m2 = 0, m3 = 0;
        int tp = 0, cur = -1;
        bool done = false;
#pragma unroll 4
        for (int e = 0; e < n; ++e) {
            const ull key = keys[e];              // induction addr -> prefetchable
            const int row = (int)(key >> 40);
            const int col = (int)(key & 0xFFull);
            const uint ib  = (uint)(key >> 8);    // inverted iou bits (low = high iou)
            const bool newrow = (row != cur);
            cur = row;
            const bool undecided = newrow || !done;
            const int w = col >> 6;
            const ull bit = 1ull << (col & 63);
            const ull mm = (w == 0) ? m0 : (w == 1) ? m1 : (w == 2) ? m2 : m3;
            const bool decide = undecided && ((mm & bit) == 0);  // best unmatched col
            const bool hit = decide && (ib <= thr_inv);          // iou >= thr
            tp += hit ? 1 : 0;
            const ull sb = hit ? bit : 0ull;
            m0 |= (w == 0) ? sb : 0ull;
            m1 |= (w == 1) ? sb : 0ull;
            m2 |= (w == 2) ? sb : 0ull;
            m3 |= (w == 3) ? sb : 0ull;
            done = decide || (done && !newrow);
        }
        // fp = NROWS - tp, fn = MCOLS - tp  =>  prec = tp / (N + M - tp)
        precs[tid] = (float)tp / (float)(NROWS + MCOLS - tp);
    }
    __syncthreads();
    if (tid == 0) {
        float s = 0.0f;
#pragma unroll
        for (int t = 0; t < NTHR; ++t) s += precs[t];
        perimg[b] = s / (float)NTHR;
    }
}

// --- Phase 3: mean over images ---
__global__ void __launch_bounds__(64) finalize_kernel(
        const float* __restrict__ perimg, float* __restrict__ out) {
    const int lane = threadIdx.x;
    float s = perimg[lane] + perimg[lane + 64];
#pragma unroll
    for (int off = 32; off; off >>= 1) s += __shfl_xor(s, off);
    if (lane == 0) out[0] = s / (float)BIMG;
}

extern "C" void kernel_launch(void* const* d_in, const int* in_sizes, int n_in,
                              void* d_out, int out_size, void* d_ws, size_t ws_size,
                              hipStream_t stream) {
    const float4* pred = (const float4*)d_in[0];
    const float4* gt   = (const float4*)d_in[1];
    float* out = (float*)d_out;

    int*   cnt     = (int*)d_ws;                                   // 128 ints
    ull*   entries = (ull*)((char*)d_ws + 512);                    // 128*CAP u64
    float* perimg  = (float*)((char*)d_ws + 512 + (size_t)BIMG * CAP * 8);

    (void)hipMemsetAsync(cnt, 0, BIMG * sizeof(int), stream);      // capturable

    // 2 row-blocks (1024 rows each) x 8 col-chunks x 128 images = 2048 blocks
    dim3 g1((NROWS + 256 * RPT - 1) / (256 * RPT), CSPLIT, BIMG);
    screen_kernel<<<g1, dim3(256), 0, stream>>>(pred, gt, cnt, entries);

    match_kernel<<<dim3(BIMG), dim3(128), 0, stream>>>(cnt, entries, perimg);

    finalize_kernel<<<dim3(1), dim3(64), 0, stream>>>(perimg, out);
}

// Round 8
// 89.724 us; speedup vs baseline: 1.8772x; 1.0005x over previous
//
#include <hip/hip_runtime.h>
#include <cstdint>

// Bit-exact vs numpy reference: no FMA contraction anywhere in this TU.
#pragma clang fp contract(off)

#define NROWS 2000   // pred boxes per image
#define MCOLS 200    // gt boxes per image
#define BIMG  128    // images
#define NTHR  5      // thresholds 0.5..0.7 step 0.05
#define CAP   768    // per-image candidate entry capacity
#define NPMAX 1024   // next pow2 >= CAP (LDS sort buffer)
#define RPT   4      // rows per thread (ILP)
#define CSPLIT 8     // column chunks per image (TLP)
#define CPB   (MCOLS / CSPLIT)   // 25 gt cols per block

// screening factor: inter >= t*uni  <=>  inter >= (t/(1+t))*(a1+a2).
// 0.4993/1.4993 = 0.333022 < 0.333200 = 0.4997/1.4997 -> every pair with
// exact IoU >= 0.4997 is flagged even with ~ulp predicate rounding.
#define CFAC 0.33302208f

typedef unsigned long long ull;

// --- Phase 1: all-pairs screen. 11 VALU ops/pair; one divergent region per
//     (column, 4 rows) instead of per pair. Hits recompute exact reference
//     IEEE IoU and push packed sort key (row asc | iou desc | col asc). ---
__global__ void __launch_bounds__(256) screen_kernel(
        const float4* __restrict__ pred, const float4* __restrict__ gt,
        int* __restrict__ counters, ull* __restrict__ entries) {
    __shared__ float4 gsh[CPB];
    __shared__ float  gar[CPB];   // a2 (exact reference product)
    __shared__ float  gca[CPB];   // CFAC * a2
    const int b    = blockIdx.z;
    const int cch  = blockIdx.y;           // column chunk
    const int tid  = threadIdx.x;
    if (tid < CPB) {
        const float4 gb = gt[b * MCOLS + cch * CPB + tid];
        const float a2 = (gb.z - gb.x) * (gb.w - gb.y);
        gsh[tid] = gb;
        gar[tid] = a2;
        gca[tid] = CFAC * a2;
    }
    __syncthreads();

    const int r0 = blockIdx.x * (256 * RPT) + tid;   // rows r0 + k*256
    float4 p[RPT];
    float  a1[RPT], ca1[RPT];
#pragma unroll
    for (int k = 0; k < RPT; ++k) {
        const int r = r0 + k * 256;
        p[k] = (r < NROWS) ? pred[b * NROWS + r]
                           : make_float4(-1.f, -1.f, -1.f, -1.f);  // never flags
        a1[k]  = (p[k].z - p[k].x) * (p[k].w - p[k].y);
        ca1[k] = CFAC * a1[k];
    }

#pragma unroll 5
    for (int j = 0; j < CPB; ++j) {
        const float4 gb  = gsh[j];         // broadcast, conflict-free
        const float  a2  = gar[j];
        const float  ca2 = gca[j];
        float inter[RPT];
        bool  h[RPT];
#pragma unroll
        for (int k = 0; k < RPT; ++k) {
            const float ltx = fmaxf(p[k].x, gb.x), lty = fmaxf(p[k].y, gb.y);
            const float rbx = fminf(p[k].z, gb.z), rby = fminf(p[k].w, gb.w);
            const float wx = fmaxf(rbx - ltx, 0.0f), wy = fmaxf(rby - lty, 0.0f);
            inter[k] = wx * wy;
            h[k] = inter[k] >= (ca1[k] + ca2);
        }
        if (h[0] | h[1] | h[2] | h[3]) {   // rare: one region per 4 pairs
#pragma unroll
            for (int k = 0; k < RPT; ++k) {
                if (h[k]) {
                    const float uni = (a1[k] + a2) - inter[k];  // reference order
                    const float iou = inter[k] / uni;           // exact IEEE
                    const int idx = atomicAdd(&counters[b], 1);
                    if (idx < CAP)
                        entries[(size_t)b * CAP + idx] =
                              ((ull)(r0 + k * 256) << 40)
                            | ((ull)(__float_as_uint(iou) ^ 0xFFFFFFFFu) << 8)
                            | (ull)(cch * CPB + j);
                }
            }
        }
    }
}

// --- Phase 2: per image: bitonic-sort candidate keys (deterministic total
//     order erases atomic append order), then 5 lanes replay exact greedy
//     branchlessly in registers (200-bit matched mask in 4 ulls). ---
__global__ void __launch_bounds__(256) match_kernel(
        const int* __restrict__ counters, const ull* __restrict__ entries,
        float* __restrict__ perimg) {
    __shared__ ull   keys[NPMAX];
    __shared__ float precs[NTHR];
    const int b = blockIdx.x;
    const int tid = threadIdx.x;
    const int n = min(counters[b], CAP);

    int np = 256;
    while (np < n) np <<= 1;                 // n<=768 -> np<=1024
    for (int i = tid; i < np; i += 256)
        keys[i] = (i < n) ? entries[(size_t)b * CAP + i] : ~0ull;  // sentinels last
    __syncthreads();

    for (int k = 2; k <= np; k <<= 1) {
        for (int j = k >> 1; j > 0; j >>= 1) {
            for (int i = tid; i < np; i += 256) {
                const int ixj = i ^ j;
                if (ixj > i) {
                    const ull a = keys[i], c = keys[ixj];
                    if ((a > c) == ((i & k) == 0)) { keys[i] = c; keys[ixj] = a; }
                }
            }
            __syncthreads();
        }
    }

    if (tid < NTHR) {
        // match np.arange(0.5, 0.75, 0.05): start + i*step in double, cast f32
        const float thr = (float)(0.5 + 0.05 * (double)tid);
        const uint thr_inv = __float_as_uint(thr) ^ 0xFFFFFFFFu;
        ull m0 = 0, m1 = 0, m2 = 0, m3 = 0;
        int tp = 0, cur = -1;
        bool done = false;
#pragma unroll 4
        for (int e = 0; e < n; ++e) {
            const ull key = keys[e];              // induction addr -> prefetchable
            const int row = (int)(key >> 40);
            const int col = (int)(key & 0xFFull);
            const uint ib  = (uint)(key >> 8);    // inverted iou bits (low = high iou)
            const bool newrow = (row != cur);
            cur = row;
            const bool undecided = newrow || !done;
            const int w = col >> 6;
            const ull bit = 1ull << (col & 63);
            const ull mm = (w == 0) ? m0 : (w == 1) ? m1 : (w == 2) ? m2 : m3;
            const bool decide = undecided && ((mm & bit) == 0);  // best unmatched col
            const bool hit = decide && (ib <= thr_inv);          // iou >= thr
            tp += hit ? 1 : 0;
            const ull sb = hit ? bit : 0ull;
            m0 |= (w == 0) ? sb : 0ull;
            m1 |= (w == 1) ? sb : 0ull;
            m2 |= (w == 2) ? sb : 0ull;
            m3 |= (w == 3) ? sb : 0ull;
            done = decide || (done && !newrow);
        }
        // fp = NROWS - tp, fn = MCOLS - tp  =>  prec = tp / (N + M - tp)
        precs[tid] = (float)tp / (float)(NROWS + MCOLS - tp);
    }
    __syncthreads();
    if (tid == 0) {
        float s = 0.0f;
#pragma unroll
        for (int t = 0; t < NTHR; ++t) s += precs[t];
        perimg[b] = s / (float)NTHR;
    }
}

// --- Phase 3: mean over images ---
__global__ void __launch_bounds__(64) finalize_kernel(
        const float* __restrict__ perimg, float* __restrict__ out) {
    const int lane = threadIdx.x;
    float s = perimg[lane] + perimg[lane + 64];
#pragma unroll
    for (int off = 32; off; off >>= 1) s += __shfl_xor(s, off);
    if (lane == 0) out[0] = s / (float)BIMG;
}

extern "C" void kernel_launch(void* const* d_in, const int* in_sizes, int n_in,
                              void* d_out, int out_size, void* d_ws, size_t ws_size,
                              hipStream_t stream) {
    const float4* pred = (const float4*)d_in[0];
    const float4* gt   = (const float4*)d_in[1];
    float* out = (float*)d_out;

    int*   cnt     = (int*)d_ws;                                   // 128 ints
    ull*   entries = (ull*)((char*)d_ws + 512);                    // 128*CAP u64
    float* perimg  = (float*)((char*)d_ws + 512 + (size_t)BIMG * CAP * 8);

    (void)hipMemsetAsync(cnt, 0, BIMG * sizeof(int), stream);      // capturable

    // 2 row-blocks (1024 rows each) x 8 col-chunks x 128 images = 2048 blocks
    dim3 g1((NROWS + 256 * RPT - 1) / (256 * RPT), CSPLIT, BIMG);
    screen_kernel<<<g1, dim3(256), 0, stream>>>(pred, gt, cnt, entries);

    match_kernel<<<dim3(BIMG), dim3(256), 0, stream>>>(cnt, entries, perimg);

    finalize_kernel<<<dim3(1), dim3(64), 0, stream>>>(perimg, out);
}